// Round 3
// baseline (113.141 us; speedup 1.0000x reference)
//
#include <hip/hip_runtime.h>
#include <math.h>

#define NN 256
#define LL 4096
#define DL 64
#define DC 128
#define KS 15
#define LOUT (LL - KS + 1)   // 4082
#define HB 2048              // positions handled by half h=0; h=1 gets LOUT-HB=2034
#define CST 133              // padded LDS row stride for ctb
#define RSQRT_DC 0.08838834764831843f

// ws layout (float offsets):
//   [0)       ctb      60*128            = 7680 floats
//   [7680)    stabb    256 * 64 (60 stab, [60]=base) = 16384 floats
//   [24064)   partials 512 * 48 (45 A, [45]=m, [46]=S) = 24576 floats
#define WS_STABB 7680
#define WS_PART  24064

// ---------------- K1: contrib table ----------------
// ctb[(v*15+k)*128 + c] = sum_i emb[v,i] * conv_w[c,i,k]
__global__ __launch_bounds__(128) void contrib_kernel(const float* __restrict__ emb,
                                                      const float* __restrict__ conv_w,
                                                      float* __restrict__ ctb) {
    const int c = blockIdx.x;
    const int tid = threadIdx.x;
    __shared__ float wsm[DL][16];
    __shared__ float es[4][DL];
    const float* wsrc = conv_w + (size_t)c * (DL * KS);
    for (int idx = tid; idx < DL * KS; idx += 128) wsm[idx / KS][idx % KS] = wsrc[idx];
    for (int idx = tid; idx < 4 * DL; idx += 128) es[idx >> 6][idx & 63] = emb[idx];
    __syncthreads();
    if (tid < 60) {
        const int v = tid / KS, k = tid % KS;
        float s = 0.f;
#pragma unroll
        for (int i = 0; i < DL; ++i) s += es[v][i] * wsm[i][k];
        ctb[tid * DC + c] = s;
    }
}

// ---------------- block reductions ----------------
template <int NW>
__device__ __forceinline__ float bsum(float v, float* red, int tid) {
#pragma unroll
    for (int off = 32; off > 0; off >>= 1) v += __shfl_down(v, off, 64);
    if ((tid & 63) == 0) red[tid >> 6] = v;
    __syncthreads();
    float r = 0.f;
#pragma unroll
    for (int w = 0; w < NW; ++w) r += red[w];
    __syncthreads();
    return r;
}

template <int NW>
__device__ __forceinline__ float bmax(float v, float* red, int tid) {
#pragma unroll
    for (int off = 32; off > 0; off >>= 1) v = fmaxf(v, __shfl_down(v, off, 64));
    if ((tid & 63) == 0) red[tid >> 6] = v;
    __syncthreads();
    float r = red[0];
#pragma unroll
    for (int w = 1; w < NW; ++w) r = fmaxf(r, red[w]);
    __syncthreads();
    return r;
}

// ---------------- K2: per-sequence scalar chain ----------------
// counts -> rm -> q -> qk -> stab[60], base  (writes ws stabb)
__global__ __launch_bounds__(256) void chain_kernel(
    const int* __restrict__ tokens, const float* __restrict__ ctb_g,
    const float* __restrict__ conv_b,
    const float* __restrict__ Wq, const float* __restrict__ bq,
    const float* __restrict__ Wk, const float* __restrict__ bk,
    float* __restrict__ ws) {
    const int n = blockIdx.x;
    const int tid = threadIdx.x;

    __shared__ unsigned tok2[256];
    __shared__ float ctb[60 * CST];
    __shared__ float rm[DC], qv[DC], qk[DC];
    __shared__ float cf[60];
    __shared__ float red4[4];
    __shared__ int totw[4][4];
    __shared__ int cnt[KS][4];

#define TOK2(p) ((tok2[(p) >> 4] >> (2 * ((p) & 15))) & 3u)

    for (int idx = tid; idx < 60 * DC; idx += 256)
        ctb[(idx >> 7) * CST + (idx & 127)] = ctb_g[idx];

    // pack 16 tokens/dword + value counts via popc
    {
        const int4* tv = (const int4*)(tokens + (size_t)n * LL) + tid * 4;
        unsigned w = 0;
#pragma unroll
        for (int m = 0; m < 4; ++m) {
            int4 t4 = tv[m];
            w |= ((unsigned)t4.x | ((unsigned)t4.y << 2) |
                  ((unsigned)t4.z << 4) | ((unsigned)t4.w << 6)) << (8 * m);
        }
        tok2[tid] = w;
        int c0, c1, c2, c3;
        unsigned y, z;
        y = w;               z = (y | (y >> 1)) & 0x55555555u; c0 = 16 - __popc(z);
        y = w ^ 0x55555555u; z = (y | (y >> 1)) & 0x55555555u; c1 = 16 - __popc(z);
        y = w ^ 0xAAAAAAAAu; z = (y | (y >> 1)) & 0x55555555u; c2 = 16 - __popc(z);
        y = w ^ 0xFFFFFFFFu; z = (y | (y >> 1)) & 0x55555555u; c3 = 16 - __popc(z);
#pragma unroll
        for (int off = 32; off > 0; off >>= 1) {
            c0 += __shfl_down(c0, off, 64); c1 += __shfl_down(c1, off, 64);
            c2 += __shfl_down(c2, off, 64); c3 += __shfl_down(c3, off, 64);
        }
        if ((tid & 63) == 0) {
            const int wv = tid >> 6;
            totw[wv][0] = c0; totw[wv][1] = c1; totw[wv][2] = c2; totw[wv][3] = c3;
        }
    }
    __syncthreads();

    if (tid < KS) {
        const int k = tid;
        int h0 = 0, h1 = 0, h2 = 0, h3 = 0;
        for (int p = 0; p < k; ++p) {
            int v = (int)TOK2(p);
            h0 += (v == 0); h1 += (v == 1); h2 += (v == 2); h3 += (v == 3);
        }
        for (int p = k + LOUT; p < LL; ++p) {
            int v = (int)TOK2(p);
            h0 += (v == 0); h1 += (v == 1); h2 += (v == 2); h3 += (v == 3);
        }
        cnt[k][0] = (totw[0][0] + totw[1][0] + totw[2][0] + totw[3][0]) - h0;
        cnt[k][1] = (totw[0][1] + totw[1][1] + totw[2][1] + totw[3][1]) - h1;
        cnt[k][2] = (totw[0][2] + totw[1][2] + totw[2][2] + totw[3][2]) - h2;
        cnt[k][3] = (totw[0][3] + totw[1][3] + totw[2][3] + totw[3][3]) - h3;
    }
    __syncthreads();
    if (tid < 60) cf[tid] = (float)cnt[tid % KS][tid / KS];
    __syncthreads();

    if (tid < DC) {
        float s = 0.f;
#pragma unroll
        for (int j = 0; j < 60; ++j) s += cf[j] * ctb[j * CST + tid];
        rm[tid] = conv_b[tid] + s * (1.0f / (float)LOUT);
    }
    __syncthreads();

    if (tid < DC) {
        const float4* wr = (const float4*)(Wq + (size_t)tid * DC);
        const float4* r4 = (const float4*)rm;
        float s = 0.f;
#pragma unroll
        for (int j = 0; j < DC / 4; ++j) {
            float4 w = wr[j], r = r4[j];
            s += w.x * r.x + w.y * r.y + w.z * r.z + w.w * r.w;
        }
        qv[tid] = s + bq[tid];
    }
    __syncthreads();

    if (tid < DC) {
        float s = 0.f;
        for (int c = 0; c < DC; ++c) s += qv[c] * Wk[(size_t)c * DC + tid];
        qk[tid] = s;
    }
    __syncthreads();

    float* sw = ws + WS_STABB + n * 64;
    if (tid < 60) {
        float s = 0.f;
#pragma unroll 4
        for (int c = 0; c < DC; ++c) s += ctb[tid * CST + c] * qk[c];
        sw[tid] = s * RSQRT_DC;
    }
    float term = 0.f;
    if (tid < DC) term = conv_b[tid] * qk[tid] + qv[tid] * bk[tid];
    const float base = bsum<4>(term, red4, tid) * RSQRT_DC;
    if (tid == 0) sw[60] = base;
#undef TOK2
}

// ---------------- K3: scores + partial softmax + partial histogram ----------------
// grid 512: block b -> sequence n=b>>1, half h=b&1 (positions [h*HB, h*HB+NP))
__global__ __launch_bounds__(512, 4) void score_kernel(
    const int* __restrict__ tokens, float* __restrict__ ws) {
    const int b = blockIdx.x;
    const int n = b >> 1, h = b & 1;
    const int t0 = h * HB;
    const int NP = h ? (LOUT - HB) : HB;
    const int tid = threadIdx.x;

    __shared__ float Tt[1024];
    __shared__ unsigned tok2[132];
    __shared__ float stabL[64];
    __shared__ float AccL[45];
    __shared__ float red8[8];

    const float* sw = ws + WS_STABB + n * 64;
    if (tid < 61) stabL[tid] = sw[tid];
    if (tid < 45) AccL[tid] = 0.f;
    if (tid >= 130 && tid < 132) tok2[tid] = 0u;

    // pack token slice [t0, t0+2080) (clamped) into 130 dwords
    if (tid < 130) {
        const int* tb = tokens + (size_t)n * LL;
        unsigned w = 0;
#pragma unroll
        for (int m = 0; m < 4; ++m) {
            int gi = t0 + tid * 16 + m * 4;
            if (gi > LL - 4) gi = LL - 4;          // clamp: overrun feeds only guarded positions
            const int4 t4 = *(const int4*)(tb + gi);
            w |= ((unsigned)t4.x | ((unsigned)t4.y << 2) |
                  ((unsigned)t4.z << 4) | ((unsigned)t4.w << 6)) << (8 * m);
        }
        tok2[tid] = w;
    }
    __syncthreads();

    const float base = stabL[60];
    // chunk tables: Tt[j*256+b] = sum_m stabL[tok_m(b)*15 + 4j+m]
    for (int e = tid; e < 1024; e += 512) {
        const int j = e >> 8, bb = e & 255;
        float s = stabL[(bb & 3) * KS + 4 * j] +
                  stabL[((bb >> 2) & 3) * KS + 4 * j + 1] +
                  stabL[((bb >> 4) & 3) * KS + 4 * j + 2];
        if (j < 3) s += stabL[((bb >> 6) & 3) * KS + 4 * j + 3];
        Tt[e] = s;
    }
    __syncthreads();

    // scores for 4 strided positions/thread, all kept in registers
    float sc[4];
    unsigned wreg[4];
    float lmax = -3.4e38f;
#pragma unroll
    for (int j = 0; j < 4; ++j) {
        const int tl = tid + 512 * j;
        if (tl < NP) {
            const unsigned dw0 = tok2[tl >> 4];
            const unsigned dw1 = tok2[(tl >> 4) + 1];
            const unsigned long long W =
                ((unsigned long long)dw0 | ((unsigned long long)dw1 << 32)) >> (2 * (tl & 15));
            const unsigned w = (unsigned)W;
            wreg[j] = w;
            sc[j] = base + Tt[w & 255] + Tt[256 + ((w >> 8) & 255)] +
                    Tt[512 + ((w >> 16) & 255)] + Tt[768 + ((w >> 24) & 63)];
            lmax = fmaxf(lmax, sc[j]);
        } else { wreg[j] = 0u; sc[j] = -3.4e38f; }
    }
    const float m = bmax<8>(lmax, red8, tid);

    float ev[4];
    float lsum = 0.f;
#pragma unroll
    for (int j = 0; j < 4; ++j) {
        const int tl = tid + 512 * j;
        ev[j] = (tl < NP) ? __expf(sc[j] - m) : 0.f;
        lsum += ev[j];
    }
    const float S = bsum<8>(lsum, red8, tid);

    // partial histogram in registers (v=0 recovered later from S)
    float a1[KS], a2[KS], a3[KS];
#pragma unroll
    for (int k = 0; k < KS; ++k) { a1[k] = 0.f; a2[k] = 0.f; a3[k] = 0.f; }
#pragma unroll
    for (int j = 0; j < 4; ++j) {
        const float e = ev[j];
        const unsigned w = wreg[j];
#pragma unroll
        for (int k = 0; k < KS; ++k) {
            const int v = (int)((w >> (2 * k)) & 3u);
            a1[k] += (v == 1) ? e : 0.f;
            a2[k] += (v == 2) ? e : 0.f;
            a3[k] += (v == 3) ? e : 0.f;
        }
    }
    {
        const int lane = tid & 63;
#pragma unroll
        for (int k = 0; k < KS; ++k) {
            float v1 = a1[k], v2 = a2[k], v3 = a3[k];
#pragma unroll
            for (int off = 32; off > 0; off >>= 1) {
                v1 += __shfl_down(v1, off, 64);
                v2 += __shfl_down(v2, off, 64);
                v3 += __shfl_down(v3, off, 64);
            }
            if (lane == 0) {
                atomicAdd(&AccL[k], v1);
                atomicAdd(&AccL[KS + k], v2);
                atomicAdd(&AccL[2 * KS + k], v3);
            }
        }
    }
    __syncthreads();

    float* P = ws + WS_PART + (size_t)(n * 2 + h) * 48;
    if (tid < 45) P[tid] = AccL[tid];
    else if (tid == 45) P[45] = m;
    else if (tid == 46) P[46] = S;
}

// ---------------- K4: combine halves + z + out ----------------
__global__ __launch_bounds__(128) void final_kernel(
    const float* __restrict__ ctb_g, const float* __restrict__ conv_b,
    const float* __restrict__ Wv, const float* __restrict__ bv,
    const float* __restrict__ ws, float* __restrict__ out) {
    const int n = blockIdx.x;
    const int tid = threadIdx.x;
    __shared__ float Acc[60];
    __shared__ float zv[DC];
    __shared__ float scs[4];   // r0, r1, invS, S

    const float* P0 = ws + WS_PART + (size_t)(n * 2) * 48;
    const float* P1 = P0 + 48;
    if (tid == 0) {
        const float m0 = P0[45], m1 = P1[45];
        const float m = fmaxf(m0, m1);
        const float r0 = __expf(m0 - m), r1 = __expf(m1 - m);
        const float S = P0[46] * r0 + P1[46] * r1;
        scs[0] = r0; scs[1] = r1; scs[2] = 1.0f / S; scs[3] = S;
    }
    __syncthreads();
    if (tid < 45) Acc[KS + tid] = P0[tid] * scs[0] + P1[tid] * scs[1];
    __syncthreads();
    if (tid < KS) Acc[tid] = scs[3] - Acc[KS + tid] - Acc[2 * KS + tid] - Acc[3 * KS + tid];
    __syncthreads();

    {
        float s = 0.f;
#pragma unroll
        for (int j = 0; j < 60; ++j) s += Acc[j] * ctb_g[j * DC + tid];
        zv[tid] = conv_b[tid] + s * scs[2];
    }
    __syncthreads();

    {
        const float4* wr = (const float4*)(Wv + (size_t)tid * DC);
        const float4* z4 = (const float4*)zv;
        float s = 0.f;
#pragma unroll
        for (int j = 0; j < DC / 4; ++j) {
            float4 w = wr[j], z = z4[j];
            s += w.x * z.x + w.y * z.y + w.z * z.z + w.w * z.w;
        }
        out[(size_t)n * DC + tid] = s + bv[tid];
    }
}

extern "C" void kernel_launch(void* const* d_in, const int* in_sizes, int n_in,
                              void* d_out, int out_size, void* d_ws, size_t ws_size,
                              hipStream_t stream) {
    const int*   tokens = (const int*)d_in[0];
    const float* emb    = (const float*)d_in[1];
    const float* conv_w = (const float*)d_in[2];
    const float* conv_b = (const float*)d_in[3];
    const float* Wq     = (const float*)d_in[4];
    const float* bq     = (const float*)d_in[5];
    const float* Wk     = (const float*)d_in[6];
    const float* bk     = (const float*)d_in[7];
    const float* Wv     = (const float*)d_in[8];
    const float* bv     = (const float*)d_in[9];
    float* out = (float*)d_out;
    float* ws  = (float*)d_ws;   // needs 194560 B

    contrib_kernel<<<DC, 128, 0, stream>>>(emb, conv_w, ws);
    chain_kernel<<<NN, 256, 0, stream>>>(tokens, ws, conv_b, Wq, bq, Wk, bk, ws);
    score_kernel<<<NN * 2, 512, 0, stream>>>(tokens, ws);
    final_kernel<<<NN, 128, 0, stream>>>(ws, conv_b, Wv, bv, ws, out);
}

// Round 4
// 100.518 us; speedup vs baseline: 1.1256x; 1.1256x over previous
//
#include <hip/hip_runtime.h>
#include <math.h>

#define NN 256
#define LL 4096
#define DL 64
#define DC 128
#define KS 15
#define LOUT (LL - KS + 1)   // 4082
#define RSQRT_DC 0.08838834764831843f
#define INV_LOUT (1.0f / (float)LOUT)

// ws layout (4-byte units):
//   [0)      ctb     60*128 floats  = 7680
//   [7680)   packed  256*256 uints  (16 tokens per dword, 2 bits each)
//   [73216)  cnt     256*4  ints    (total token-value counts per seq)
#define WS_CTB  0
#define WS_PACK 7680
#define WS_CNT  73216

// ---------------- K1: token pack+counts (blocks 0..255) + contrib table (blocks 256..383) ----------------
__global__ __launch_bounds__(256) void prep_kernel(const int* __restrict__ tokens,
                                                   const float* __restrict__ emb,
                                                   const float* __restrict__ conv_w,
                                                   float* __restrict__ ws) {
    const int b = blockIdx.x, tid = threadIdx.x;
    if (b < NN) {
        __shared__ int totw[4][4];
        const int n = b;
        const int4* tv = (const int4*)(tokens + (size_t)n * LL) + tid * 4;
        unsigned w = 0;
#pragma unroll
        for (int m = 0; m < 4; ++m) {
            int4 t4 = tv[m];
            w |= ((unsigned)t4.x | ((unsigned)t4.y << 2) |
                  ((unsigned)t4.z << 4) | ((unsigned)t4.w << 6)) << (8 * m);
        }
        ((unsigned*)ws)[WS_PACK + n * 256 + tid] = w;
        int c0, c1, c2, c3;
        unsigned y, z;
        y = w;               z = (y | (y >> 1)) & 0x55555555u; c0 = 16 - __popc(z);
        y = w ^ 0x55555555u; z = (y | (y >> 1)) & 0x55555555u; c1 = 16 - __popc(z);
        y = w ^ 0xAAAAAAAAu; z = (y | (y >> 1)) & 0x55555555u; c2 = 16 - __popc(z);
        y = w ^ 0xFFFFFFFFu; z = (y | (y >> 1)) & 0x55555555u; c3 = 16 - __popc(z);
#pragma unroll
        for (int off = 32; off > 0; off >>= 1) {
            c0 += __shfl_down(c0, off, 64); c1 += __shfl_down(c1, off, 64);
            c2 += __shfl_down(c2, off, 64); c3 += __shfl_down(c3, off, 64);
        }
        if ((tid & 63) == 0) {
            const int wv = tid >> 6;
            totw[wv][0] = c0; totw[wv][1] = c1; totw[wv][2] = c2; totw[wv][3] = c3;
        }
        __syncthreads();
        if (tid < 4)
            ((int*)ws)[WS_CNT + n * 4 + tid] =
                totw[0][tid] + totw[1][tid] + totw[2][tid] + totw[3][tid];
    } else {
        const int c = b - NN;
        __shared__ float wsm[DL][16];
        __shared__ float es[4][DL];
        const float* wsrc = conv_w + (size_t)c * (DL * KS);
        for (int idx = tid; idx < DL * KS; idx += 256) wsm[idx / KS][idx % KS] = wsrc[idx];
        es[tid >> 6][tid & 63] = emb[tid];
        __syncthreads();
        if (tid < 60) {
            const int v = tid / KS, k = tid % KS;
            float s = 0.f;
#pragma unroll
            for (int i = 0; i < DL; ++i) s += es[v][i] * wsm[i][k];
            ws[WS_CTB + tid * DC + c] = s;
        }
    }
}

template <int NW>
__device__ __forceinline__ float bsum(float v, float* red, int tid) {
#pragma unroll
    for (int off = 32; off > 0; off >>= 1) v += __shfl_down(v, off, 64);
    if ((tid & 63) == 0) red[tid >> 6] = v;
    __syncthreads();
    float r = 0.f;
#pragma unroll
    for (int w = 0; w < NW; ++w) r += red[w];
    __syncthreads();
    return r;
}

template <int NW>
__device__ __forceinline__ float bmax(float v, float* red, int tid) {
#pragma unroll
    for (int off = 32; off > 0; off >>= 1) v = fmaxf(v, __shfl_down(v, off, 64));
    if ((tid & 63) == 0) red[tid >> 6] = v;
    __syncthreads();
    float r = red[0];
#pragma unroll
    for (int w = 1; w < NW; ++w) r = fmaxf(r, red[w]);
    __syncthreads();
    return r;
}

// ---------------- K2: everything per sequence, one block, one barrier-light pass ----------------
// wave0 runs the scalar chain wave-synchronously (no barriers) while waves 1-7 stage tokens.
__global__ __launch_bounds__(512) void encode_kernel(
    const float* __restrict__ ws, const float* __restrict__ conv_b,
    const float* __restrict__ Wq, const float* __restrict__ bq,
    const float* __restrict__ Wk, const float* __restrict__ bk,
    const float* __restrict__ Wv, const float* __restrict__ bv,
    float* __restrict__ out) {
    const int n = blockIdx.x, tid = threadIdx.x;
    const float* ctb = ws + WS_CTB;
    const unsigned* packed = (const unsigned*)ws + WS_PACK;

    __shared__ unsigned tok2L[258];
    __shared__ float stabL[64];
    __shared__ float cfL[60];
    __shared__ float rmL[DC], qvL[DC], qkL[DC], zvL[DC];
    __shared__ float Tt[1024];
    __shared__ float AccL[45];
    __shared__ float red[8];

    if (tid >= 64) {
        const int i = tid - 64;
        if (i < 258) tok2L[i] = (i < 256) ? packed[n * 256 + i] : 0u;
        else if (i < 258 + 45) AccL[i - 258] = 0.f;
    } else {
        // ======== wave0: counts -> rm -> q -> qk -> stab/base, wave-synchronous ========
        const int l = tid;
        const int4 ct = *(const int4*)((const int*)ws + WS_CNT + n * 4);
        const unsigned dwF = packed[n * 256];          // tokens 0..15
        const unsigned dwL = packed[n * 256 + 255];    // tokens 4080..4095
        if (l < KS) {
            const int k = l;
            const unsigned pm = (k == 0) ? 0u : ((1u << (2 * k)) - 1u);          // slots [0,k)
            const unsigned sm = (k == 14) ? 0u : (0xFFFFFFFFu << (2 * (k + 2))); // slots [k+2,16)
            const int tot4[4] = {ct.x, ct.y, ct.z, ct.w};
#pragma unroll
            for (int v = 0; v < 4; ++v) {
                const unsigned patt = (unsigned)v * 0x55555555u;
                unsigned yf = dwF ^ patt, zf = (yf | (yf >> 1)) & 0x55555555u;
                unsigned yl = dwL ^ patt, zl = (yl | (yl >> 1)) & 0x55555555u;
                const int pre = k - __popc(zf & pm);          // #v in [0,k)
                const int suf = (14 - k) - __popc(zl & sm);   // #v in [k+LOUT, LL)
                cfL[v * KS + k] = (float)(tot4[v] - pre - suf);
            }
        }
        const int c0 = 2 * l, c1 = 2 * l + 1;
        // rm
        float r0 = 0.f, r1 = 0.f;
        for (int j = 0; j < 60; ++j) {
            const float cfj = cfL[j];
            const float2 cb = *(const float2*)(ctb + j * DC + c0);
            r0 += cfj * cb.x; r1 += cfj * cb.y;
        }
        const float2 cb2 = *(const float2*)(conv_b + c0);
        r0 = cb2.x + r0 * INV_LOUT; r1 = cb2.y + r1 * INV_LOUT;
        rmL[c0] = r0; rmL[c1] = r1;
        // q = rm @ Wq.T + bq
        const float4* wq0 = (const float4*)(Wq + (size_t)c0 * DC);
        const float4* wq1 = (const float4*)(Wq + (size_t)c1 * DC);
        const float4* rr = (const float4*)rmL;
        float s0 = 0.f, s1 = 0.f;
#pragma unroll 8
        for (int j = 0; j < 32; ++j) {
            const float4 r = rr[j], a = wq0[j], b = wq1[j];
            s0 += a.x * r.x + a.y * r.y + a.z * r.z + a.w * r.w;
            s1 += b.x * r.x + b.y * r.y + b.z * r.z + b.w * r.w;
        }
        const float2 bq2 = *(const float2*)(bq + c0);
        const float qv0 = s0 + bq2.x, qv1 = s1 + bq2.y;
        qvL[c0] = qv0; qvL[c1] = qv1;
        // qk[d] = sum_c q[c] * Wk[c,d]  (coalesced columns)
        float k0 = 0.f, k1 = 0.f;
        const float4* qq = (const float4*)qvL;
        for (int c4 = 0; c4 < 32; ++c4) {
            const float4 q4 = qq[c4];
            const float2 w0 = *(const float2*)(Wk + (size_t)(4 * c4 + 0) * DC + c0);
            const float2 w1 = *(const float2*)(Wk + (size_t)(4 * c4 + 1) * DC + c0);
            const float2 w2 = *(const float2*)(Wk + (size_t)(4 * c4 + 2) * DC + c0);
            const float2 w3 = *(const float2*)(Wk + (size_t)(4 * c4 + 3) * DC + c0);
            k0 += q4.x * w0.x + q4.y * w1.x + q4.z * w2.x + q4.w * w3.x;
            k1 += q4.x * w0.y + q4.y * w1.y + q4.z * w2.y + q4.w * w3.y;
        }
        qkL[c0] = k0; qkL[c1] = k1;
        // stab[j] = (ctb[j] . qk) / sqrt(DC)
        if (l < 60) {
            const float4* cr = (const float4*)(ctb + (size_t)l * DC);
            const float4* qk4 = (const float4*)qkL;
            float s = 0.f;
#pragma unroll 8
            for (int t = 0; t < 32; ++t) {
                const float4 a = cr[t], q = qk4[t];
                s += a.x * q.x + a.y * q.y + a.z * q.z + a.w * q.w;
            }
            stabL[l] = s * RSQRT_DC;
        }
        // base = (conv_b . qk + q . bk) / sqrt(DC)
        const float2 bk2 = *(const float2*)(bk + c0);
        float t = cb2.x * k0 + cb2.y * k1 + qv0 * bk2.x + qv1 * bk2.y;
#pragma unroll
        for (int off = 32; off > 0; off >>= 1) t += __shfl_down(t, off, 64);
        if (l == 0) stabL[60] = t * RSQRT_DC;
    }
    __syncthreads();

    // ---- chunk tables: Tt[j*256+b] = sum_m stab[tok_m(b)*15 + 4j+m] ----
    const float base = stabL[60];
    for (int e = tid; e < 1024; e += 512) {
        const int j = e >> 8, bb = e & 255;
        float s = stabL[(bb & 3) * KS + 4 * j] +
                  stabL[((bb >> 2) & 3) * KS + 4 * j + 1] +
                  stabL[((bb >> 4) & 3) * KS + 4 * j + 2];
        if (j < 3) s += stabL[((bb >> 6) & 3) * KS + 4 * j + 3];
        Tt[e] = s;
    }
    __syncthreads();

    // ---- scores: 8 consecutive positions/thread from a 64-bit register window ----
    const unsigned d0 = tok2L[tid >> 1], d1 = tok2L[(tid >> 1) + 1];
    const unsigned long long W = (unsigned long long)d0 | ((unsigned long long)d1 << 32);
    const int sbase = (tid & 1) << 4;
    const int t0 = tid * 8;
    float sc[8];
    float lmax = -3.4e38f;
#pragma unroll
    for (int p = 0; p < 8; ++p) {
        const unsigned w = (unsigned)(W >> (sbase + 2 * p));
        const float s = base + Tt[w & 255] + Tt[256 + ((w >> 8) & 255)] +
                        Tt[512 + ((w >> 16) & 255)] + Tt[768 + ((w >> 24) & 63)];
        sc[p] = (t0 + p < LOUT) ? s : -3.4e38f;
        lmax = fmaxf(lmax, sc[p]);
    }
    const float m = bmax<8>(lmax, red, tid);
    float lsum = 0.f;
#pragma unroll
    for (int p = 0; p < 8; ++p) {
        const float e = (t0 + p < LOUT) ? __expf(sc[p] - m) : 0.f;
        sc[p] = e; lsum += e;
    }
    const float S = bsum<8>(lsum, red, tid);
    const float invS = 1.0f / S;

    // ---- attn-weighted histogram (v=0 recovered from S) ----
    float a1[KS], a2[KS], a3[KS];
#pragma unroll
    for (int k = 0; k < KS; ++k) { a1[k] = 0.f; a2[k] = 0.f; a3[k] = 0.f; }
#pragma unroll
    for (int p = 0; p < 8; ++p) {
        const float e = sc[p];
        const unsigned w = (unsigned)(W >> (sbase + 2 * p));
#pragma unroll
        for (int k = 0; k < KS; ++k) {
            const int v = (int)((w >> (2 * k)) & 3u);
            a1[k] += (v == 1) ? e : 0.f;
            a2[k] += (v == 2) ? e : 0.f;
            a3[k] += (v == 3) ? e : 0.f;
        }
    }
    {
        const int lane = tid & 63;
#pragma unroll
        for (int k = 0; k < KS; ++k) {
            float v1 = a1[k], v2 = a2[k], v3 = a3[k];
#pragma unroll
            for (int off = 32; off > 0; off >>= 1) {
                v1 += __shfl_down(v1, off, 64);
                v2 += __shfl_down(v2, off, 64);
                v3 += __shfl_down(v3, off, 64);
            }
            if (lane == 0) {
                atomicAdd(&AccL[k], v1);
                atomicAdd(&AccL[KS + k], v2);
                atomicAdd(&AccL[2 * KS + k], v3);
            }
        }
    }
    __syncthreads();

    // ---- z = conv_b + (1/S) * sum_j Acc[j] * ctb[j] ----
    if (tid < DC) {
        float s = 0.f;
#pragma unroll
        for (int k = 0; k < KS; ++k) {
            const float a0 = S - AccL[k] - AccL[KS + k] - AccL[2 * KS + k];
            s += a0 * ctb[k * DC + tid];
        }
#pragma unroll
        for (int j = KS; j < 60; ++j) s += AccL[j - KS] * ctb[j * DC + tid];
        zvL[tid] = conv_b[tid] + s * invS;
    }
    __syncthreads();

    // ---- out = z @ Wv.T + bv ----
    if (tid < DC) {
        const float4* wr = (const float4*)(Wv + (size_t)tid * DC);
        const float4* z4 = (const float4*)zvL;
        float s = 0.f;
#pragma unroll 8
        for (int j = 0; j < 32; ++j) {
            const float4 w = wr[j], z = z4[j];
            s += w.x * z.x + w.y * z.y + w.z * z.z + w.w * z.w;
        }
        out[(size_t)n * DC + tid] = s + bv[tid];
    }
}

extern "C" void kernel_launch(void* const* d_in, const int* in_sizes, int n_in,
                              void* d_out, int out_size, void* d_ws, size_t ws_size,
                              hipStream_t stream) {
    const int*   tokens = (const int*)d_in[0];
    const float* emb    = (const float*)d_in[1];
    const float* conv_w = (const float*)d_in[2];
    const float* conv_b = (const float*)d_in[3];
    const float* Wq     = (const float*)d_in[4];
    const float* bq     = (const float*)d_in[5];
    const float* Wk     = (const float*)d_in[6];
    const float* bk     = (const float*)d_in[7];
    const float* Wv     = (const float*)d_in[8];
    const float* bv     = (const float*)d_in[9];
    float* out = (float*)d_out;
    float* ws  = (float*)d_ws;   // needs ~300 KB

    prep_kernel<<<NN + DC, 256, 0, stream>>>(tokens, emb, conv_w, ws);
    encode_kernel<<<NN, 512, 0, stream>>>(ws, conv_b, Wq, bq, Wk, bk, Wv, bv, out);
}